// Round 1
// baseline (68120.691 us; speedup 1.0000x reference)
//
#include <hip/hip_runtime.h>
#include <cstddef>

#define LRC 0.001f
#define DEC 0.99f

// ---------------- workspace layout (float offsets) ----------------
static const size_t OFF_Z1P = 0;            // [32][2048]
static const size_t OFF_Z2P = 65536;        // [32][2048]
static const size_t OFF_Z2Q = 131072;
static const size_t OFF_Z3P = 196608;
static const size_t OFF_Z3Q = 262144;
static const size_t OFF_Z4P = 327680;       // [32][768]
static const size_t OFF_Z4Q = 352256;
static const size_t OFF_H1F = 376832;       // 2048 each below
static const size_t OFF_H1Q = 378880;
static const size_t OFF_H2F = 380928;
static const size_t OFF_H2Q = 382976;
static const size_t OFF_H3F = 385024;
static const size_t OFF_H3Q = 387072;
static const size_t OFF_D4F = 389120;       // 768
static const size_t OFF_D4Q = 389888;       // 768
static const size_t OFF_D3F = 390656;       // 2048
static const size_t OFF_D3Q = 392704;
static const size_t OFF_D2F = 394752;
static const size_t OFF_D2Q = 396800;
static const size_t OFF_D1F = 398848;
static const size_t OFF_D1Q = 400896;
static const size_t OFF_NSQ = 402944;       // 16: 0=x,1=h1,2=h2,3=h3,4=d4
static const size_t OFF_SL3 = 402960;       // 256 per-block |d3|^2 partials
static const size_t OFF_SL2 = 403216;
static const size_t OFF_SL1 = 403472;
static const size_t OFF_BUF = 403728;       // 2 (ping-pong EMA buffer)
static const size_t OFF_MSUM = 403732;      // [32][768]
static const size_t OFF_HA  = 428308;       // 1024*2048
static const size_t OFF_HB  = 2525460;      // 1024*2048  (end = 4622612 floats ~18.5 MB)

__device__ inline void fma4(float4& a, float s, const float4& w) {
    a.x += s * w.x; a.y += s * w.y; a.z += s * w.z; a.w += s * w.w;
}

__device__ float block_reduce_512(float v) {
    __shared__ float red[512];
    int t = threadIdx.x;
    red[t] = v;
    __syncthreads();
    for (int s = 256; s > 0; s >>= 1) {
        if (t < s) red[t] += red[t + s];
        __syncthreads();
    }
    float r = red[0];
    __syncthreads();
    return r;
}

// ---------- phase 1: z1 partials = x @ W1  (K=768, N=2048, P=32) ----------
__global__ __launch_bounds__(512) void k_fwd1(const float* __restrict__ xt,
                                              const float* __restrict__ W1,
                                              float* __restrict__ z1p,
                                              const int* __restrict__ flag) {
    if (*flag == 0) return;
    int b = blockIdx.x;               // 256 blocks
    int g = b >> 5, p = b & 31;       // g<8: 256-col group; p: K-split (24 rows)
    int tid = threadIdx.x, w = tid >> 6, lane = tid & 63;
    int c0 = g * 256 + lane * 4;
    int kb = p * 24 + w * 3;
    float4 acc = make_float4(0.f, 0.f, 0.f, 0.f);
#pragma unroll
    for (int r = 0; r < 3; ++r) {
        float a = xt[kb + r];
        const float4 wv = *(const float4*)(W1 + (size_t)(kb + r) * 2048 + c0);
        fma4(acc, a, wv);
    }
    __shared__ float4 red[8][64];
    red[w][lane] = acc;
    __syncthreads();
    if (w == 0) {
        float4 s = red[0][lane];
#pragma unroll
        for (int q = 1; q < 8; ++q) {
            float4 r2 = red[q][lane];
            s.x += r2.x; s.y += r2.y; s.z += r2.z; s.w += r2.w;
        }
        *(float4*)(z1p + (size_t)p * 2048 + c0) = s;
    }
}

// ---------- phases 2-4: fused base+decayed matvec (K=2048) ----------
// zinQ == null: layer-2 (h' = 0.99*h exactly). else h=relu(sum+b), h'=relu(0.99*(sumq+b)).
__global__ __launch_bounds__(512) void k_fwd2(const float* __restrict__ zinP,
                                              const float* __restrict__ zinQ,
                                              const float* __restrict__ bin,
                                              const float* __restrict__ W, int Nout,
                                              float* __restrict__ zoutP,
                                              float* __restrict__ zoutQ,
                                              const int* __restrict__ flag) {
    if (*flag == 0) return;
    int b = blockIdx.x;
    int g = b >> 5, p = b & 31;
    int tid = threadIdx.x, w = tid >> 6, lane = tid & 63;
    __shared__ float hs[64], hq[64];
    if (tid < 64) {
        int k = p * 64 + tid;
        float s = 0.f;
#pragma unroll 8
        for (int pp = 0; pp < 32; ++pp) s += zinP[pp * 2048 + k];
        float bv = bin[k];
        float h = fmaxf(s + bv, 0.f);
        float hqq;
        if (zinQ) {
            float sq = 0.f;
#pragma unroll 8
            for (int pp = 0; pp < 32; ++pp) sq += zinQ[pp * 2048 + k];
            hqq = fmaxf(DEC * (sq + bv), 0.f);
        } else {
            hqq = DEC * h;
        }
        hs[tid] = h; hq[tid] = hqq;
    }
    __syncthreads();
    int c0 = g * 256 + lane * 4;
    float4 ap = make_float4(0.f, 0.f, 0.f, 0.f);
    float4 aq = make_float4(0.f, 0.f, 0.f, 0.f);
#pragma unroll
    for (int r = 0; r < 8; ++r) {
        int kk = w * 8 + r;
        float a = hs[kk], a2 = hq[kk];
        const float4 wv = *(const float4*)(W + (size_t)(p * 64 + kk) * Nout + c0);
        fma4(ap, a, wv);
        fma4(aq, a2, wv);
    }
    __shared__ float4 redP[8][64];
    __shared__ float4 redQ[8][64];
    redP[w][lane] = ap; redQ[w][lane] = aq;
    __syncthreads();
    if (w == 0) {
        float4 sp = redP[0][lane], sq4 = redQ[0][lane];
#pragma unroll
        for (int q = 1; q < 8; ++q) {
            float4 r2 = redP[q][lane]; sp.x += r2.x; sp.y += r2.y; sp.z += r2.z; sp.w += r2.w;
            float4 r3 = redQ[q][lane]; sq4.x += r3.x; sq4.y += r3.y; sq4.z += r3.z; sq4.w += r3.w;
        }
        *(float4*)(zoutP + (size_t)p * Nout + c0) = sp;
        *(float4*)(zoutQ + (size_t)p * Nout + c0) = sq4;
    }
}

// ---------- phase 4b: finalize h vectors, deltas at L4, norms ----------
__global__ __launch_bounds__(512) void k_fin(float* __restrict__ wsf,
                                             const float* __restrict__ xt,
                                             const float* __restrict__ b1,
                                             const float* __restrict__ b2,
                                             const float* __restrict__ b3,
                                             const float* __restrict__ b4,
                                             const int* __restrict__ flag) {
    if (*flag == 0) return;
    int b = blockIdx.x, tid = threadIdx.x;
    if (b < 16) {
        if (tid < 128) {
            int e = b * 128 + tid;
            float s = 0.f;
#pragma unroll 8
            for (int pp = 0; pp < 32; ++pp) s += wsf[OFF_Z1P + pp * 2048 + e];
            float h = fmaxf(s + b1[e], 0.f);
            wsf[OFF_H1F + e] = h;
            wsf[OFF_H1Q + e] = DEC * h;
        }
    } else if (b < 32) {
        if (tid < 128) {
            int e = (b - 16) * 128 + tid;
            float s = 0.f, sq = 0.f;
#pragma unroll 8
            for (int pp = 0; pp < 32; ++pp) {
                s += wsf[OFF_Z2P + pp * 2048 + e];
                sq += wsf[OFF_Z2Q + pp * 2048 + e];
            }
            float bv = b2[e];
            wsf[OFF_H2F + e] = fmaxf(s + bv, 0.f);
            wsf[OFF_H2Q + e] = fmaxf(DEC * (sq + bv), 0.f);
        }
    } else if (b < 48) {
        if (tid < 128) {
            int e = (b - 32) * 128 + tid;
            float s = 0.f, sq = 0.f;
#pragma unroll 8
            for (int pp = 0; pp < 32; ++pp) {
                s += wsf[OFF_Z3P + pp * 2048 + e];
                sq += wsf[OFF_Z3Q + pp * 2048 + e];
            }
            float bv = b3[e];
            wsf[OFF_H3F + e] = fmaxf(s + bv, 0.f);
            wsf[OFF_H3Q + e] = fmaxf(DEC * (sq + bv), 0.f);
        }
    } else if (b == 48) {
        for (int e = tid; e < 768; e += 512) {
            float s = 0.f, sq = 0.f;
#pragma unroll 8
            for (int pp = 0; pp < 32; ++pp) {
                s += wsf[OFF_Z4P + pp * 768 + e];
                sq += wsf[OFF_Z4Q + pp * 768 + e];
            }
            float bv = b4[e], tv = xt[e];
            float pred = s + bv;
            float predq = DEC * (sq + bv);
            wsf[OFF_D4F + e] = 2.f * (pred - tv) * (1.f / 768.f);
            wsf[OFF_D4Q + e] = 2.f * (predq - tv) * (1.f / 768.f);
        }
    } else if (b == 49) {             // ||x||^2
        float v = 0.f;
        for (int e = tid; e < 768; e += 512) { float xv = xt[e]; v += xv * xv; }
        float s = block_reduce_512(v);
        if (tid == 0) wsf[OFF_NSQ + 0] = s;
    } else if (b == 50) {             // ||h1||^2
        float v = 0.f;
        for (int e = tid; e < 2048; e += 512) {
            float s = 0.f;
#pragma unroll 8
            for (int pp = 0; pp < 32; ++pp) s += wsf[OFF_Z1P + pp * 2048 + e];
            float h = fmaxf(s + b1[e], 0.f);
            v += h * h;
        }
        float s = block_reduce_512(v);
        if (tid == 0) wsf[OFF_NSQ + 1] = s;
    } else if (b == 51) {             // ||h2||^2
        float v = 0.f;
        for (int e = tid; e < 2048; e += 512) {
            float s = 0.f;
#pragma unroll 8
            for (int pp = 0; pp < 32; ++pp) s += wsf[OFF_Z2P + pp * 2048 + e];
            float h = fmaxf(s + b2[e], 0.f);
            v += h * h;
        }
        float s = block_reduce_512(v);
        if (tid == 0) wsf[OFF_NSQ + 2] = s;
    } else if (b == 52) {             // ||h3||^2
        float v = 0.f;
        for (int e = tid; e < 2048; e += 512) {
            float s = 0.f;
#pragma unroll 8
            for (int pp = 0; pp < 32; ++pp) s += wsf[OFF_Z3P + pp * 2048 + e];
            float h = fmaxf(s + b3[e], 0.f);
            v += h * h;
        }
        float s = block_reduce_512(v);
        if (tid == 0) wsf[OFF_NSQ + 3] = s;
    } else if (b == 53) {             // ||d4||^2
        float v = 0.f;
        for (int e = tid; e < 768; e += 512) {
            float s = 0.f;
#pragma unroll 8
            for (int pp = 0; pp < 32; ++pp) s += wsf[OFF_Z4P + pp * 768 + e];
            float d = 2.f * ((s + b4[e]) - xt[e]) * (1.f / 768.f);
            v += d * d;
        }
        float s = block_reduce_512(v);
        if (tid == 0) wsf[OFF_NSQ + 4] = s;
    }
}

// ---------- phases 5-7: fused W^T backward, wave-per-row, final outputs ----------
__global__ __launch_bounds__(512) void k_bwd(const float* __restrict__ W, int K,
                                             const float* __restrict__ dinP,
                                             const float* __restrict__ dinQ,
                                             const float* __restrict__ hP,
                                             const float* __restrict__ hQ,
                                             float* __restrict__ doutP,
                                             float* __restrict__ doutQ,
                                             float* __restrict__ slot,
                                             const int* __restrict__ flag) {
    if (*flag == 0) return;
    __shared__ float dsP[2048];
    __shared__ float dsQ[2048];
    int tid = threadIdx.x;
    for (int k = tid; k < K; k += 512) { dsP[k] = dinP[k]; dsQ[k] = dinQ[k]; }
    __syncthreads();
    int w = tid >> 6, lane = tid & 63;
    int j = blockIdx.x * 8 + w;
    const float* row = W + (size_t)j * K;
    float ap = 0.f, aq = 0.f;
    for (int k4 = lane * 4; k4 < K; k4 += 256) {
        const float4 wv = *(const float4*)(row + k4);
        ap += wv.x * dsP[k4] + wv.y * dsP[k4 + 1] + wv.z * dsP[k4 + 2] + wv.w * dsP[k4 + 3];
        aq += wv.x * dsQ[k4] + wv.y * dsQ[k4 + 1] + wv.z * dsQ[k4 + 2] + wv.w * dsQ[k4 + 3];
    }
#pragma unroll
    for (int off = 32; off > 0; off >>= 1) {
        ap += __shfl_down(ap, off);
        aq += __shfl_down(aq, off);
    }
    __shared__ float sqw[8];
    if (lane == 0) {
        float dp = (hP[j] > 0.f) ? ap : 0.f;
        float dq = (hQ[j] > 0.f) ? DEC * aq : 0.f;
        doutP[j] = dp;
        doutQ[j] = dq;
        sqw[w] = dp * dp;
    }
    __syncthreads();
    if (tid == 0) {
        float s = 0.f;
#pragma unroll
        for (int q = 0; q < 8; ++q) s += sqw[q];
        slot[blockIdx.x] = s;
    }
}

// ---------- phase 8: cond + rank-1 update of all params ----------
__global__ __launch_bounds__(512) void k_upd(int step, float* __restrict__ wsf,
                                             float* __restrict__ W1, float* __restrict__ b1,
                                             float* __restrict__ W2, float* __restrict__ b2,
                                             float* __restrict__ W3, float* __restrict__ b3,
                                             float* __restrict__ W4, float* __restrict__ b4,
                                             const float* __restrict__ xt,
                                             const int* __restrict__ flag) {
    if (*flag == 0) return;
    int tid = threadIdx.x, b = blockIdx.x;
    float s3 = block_reduce_512((tid < 256) ? wsf[OFF_SL3 + tid] : 0.f);
    float s2 = block_reduce_512((tid < 256) ? wsf[OFF_SL2 + tid] : 0.f);
    float s1 = block_reduce_512((tid < 256) ? wsf[OFF_SL1 + tid] : 0.f);
    __shared__ float condsh;
    if (tid == 0) {
        float nx = sqrtf(wsf[OFF_NSQ + 0]);
        float nh1 = sqrtf(wsf[OFF_NSQ + 1]);
        float nh2 = sqrtf(wsf[OFF_NSQ + 2]);
        float nh3 = sqrtf(wsf[OFF_NSQ + 3]);
        float nd4 = sqrtf(wsf[OFF_NSQ + 4]);
        float nd3 = sqrtf(s3), nd2 = sqrtf(s2), nd1 = sqrtf(s1);
        // leaf order: W1,b1,W2,b2,W3,b3,W4,b4
        float surprise = nx * nd1 + nd1 + nh1 * nd2 + nd2 + nh2 * nd3 + nd3 + nh3 * nd4 + nd4;
        float bufold = wsf[OFF_BUF + (step & 1)];
        float bufnew = (step == 0) ? surprise : (0.9f * bufold + 0.1f * surprise);
        wsf[OFF_BUF + ((step + 1) & 1)] = bufnew;   // all blocks write identical value
        condsh = (bufnew > 0.1f) ? 1.f : 0.f;
    }
    __syncthreads();
    if (condsh == 0.f) return;

    const float* d1q = wsf + OFF_D1Q;
    const float* d2q = wsf + OFF_D2Q;
    const float* d3q = wsf + OFF_D3Q;
    const float* d4q = wsf + OFF_D4Q;
    const float* h1q = wsf + OFF_H1Q;
    const float* h2q = wsf + OFF_H2Q;
    const float* h3q = wsf + OFF_H3Q;
    int c = tid * 4;
    {   // W1: 768 rows x 2048; 3 rows per block
        float4 dv = *(const float4*)(d1q + c);
#pragma unroll
        for (int r = 0; r < 3; ++r) {
            int i = b * 3 + r;
            float u = LRC * xt[i];
            float4* wp = (float4*)(W1 + (size_t)i * 2048 + c);
            float4 wv = *wp;
            wv.x = DEC * wv.x - u * dv.x; wv.y = DEC * wv.y - u * dv.y;
            wv.z = DEC * wv.z - u * dv.z; wv.w = DEC * wv.w - u * dv.w;
            *wp = wv;
        }
    }
    {   // W2: 2048x2048; 8 rows per block
        float4 dv = *(const float4*)(d2q + c);
#pragma unroll
        for (int r = 0; r < 8; ++r) {
            int i = b * 8 + r;
            float u = LRC * h1q[i];
            float4* wp = (float4*)(W2 + (size_t)i * 2048 + c);
            float4 wv = *wp;
            wv.x = DEC * wv.x - u * dv.x; wv.y = DEC * wv.y - u * dv.y;
            wv.z = DEC * wv.z - u * dv.z; wv.w = DEC * wv.w - u * dv.w;
            *wp = wv;
        }
    }
    {   // W3
        float4 dv = *(const float4*)(d3q + c);
#pragma unroll
        for (int r = 0; r < 8; ++r) {
            int i = b * 8 + r;
            float u = LRC * h2q[i];
            float4* wp = (float4*)(W3 + (size_t)i * 2048 + c);
            float4 wv = *wp;
            wv.x = DEC * wv.x - u * dv.x; wv.y = DEC * wv.y - u * dv.y;
            wv.z = DEC * wv.z - u * dv.z; wv.w = DEC * wv.w - u * dv.w;
            *wp = wv;
        }
    }
    if (tid < 192) {   // W4: 2048x768; 8 rows per block
        float4 dv = *(const float4*)(d4q + c);
#pragma unroll
        for (int r = 0; r < 8; ++r) {
            int i = b * 8 + r;
            float u = LRC * h3q[i];
            float4* wp = (float4*)(W4 + (size_t)i * 768 + c);
            float4 wv = *wp;
            wv.x = DEC * wv.x - u * dv.x; wv.y = DEC * wv.y - u * dv.y;
            wv.z = DEC * wv.z - u * dv.z; wv.w = DEC * wv.w - u * dv.w;
            *wp = wv;
        }
    }
    if (b == 0) {
        float4 dv = *(const float4*)(d1q + c);
        float4* bp = (float4*)(b1 + c);
        float4 bv = *bp;
        bv.x = DEC * bv.x - LRC * dv.x; bv.y = DEC * bv.y - LRC * dv.y;
        bv.z = DEC * bv.z - LRC * dv.z; bv.w = DEC * bv.w - LRC * dv.w;
        *bp = bv;
    } else if (b == 1) {
        float4 dv = *(const float4*)(d2q + c);
        float4* bp = (float4*)(b2 + c);
        float4 bv = *bp;
        bv.x = DEC * bv.x - LRC * dv.x; bv.y = DEC * bv.y - LRC * dv.y;
        bv.z = DEC * bv.z - LRC * dv.z; bv.w = DEC * bv.w - LRC * dv.w;
        *bp = bv;
    } else if (b == 2) {
        float4 dv = *(const float4*)(d3q + c);
        float4* bp = (float4*)(b3 + c);
        float4 bv = *bp;
        bv.x = DEC * bv.x - LRC * dv.x; bv.y = DEC * bv.y - LRC * dv.y;
        bv.z = DEC * bv.z - LRC * dv.z; bv.w = DEC * bv.w - LRC * dv.w;
        *bp = bv;
    } else if (b == 3 && tid < 192) {
        float4 dv = *(const float4*)(d4q + c);
        float4* bp = (float4*)(b4 + c);
        float4 bv = *bp;
        bv.x = DEC * bv.x - LRC * dv.x; bv.y = DEC * bv.y - LRC * dv.y;
        bv.z = DEC * bv.z - LRC * dv.z; bv.w = DEC * bv.w - LRC * dv.w;
        *bp = bv;
    }
}

// ---------- final batch forward: fp32 tiled GEMM C = act(A@W + bias) ----------
// BM=64, BN=128, BK=16, 256 threads, 8x4 per thread
__global__ __launch_bounds__(256) void k_gemm(const float* __restrict__ A,
                                              const float* __restrict__ W,
                                              const float* __restrict__ bias,
                                              float* __restrict__ C,
                                              int M, int N, int K, int do_relu) {
    __shared__ float sA[16][64];
    __shared__ float sB[16][128];
    int bn = blockIdx.x, bm = blockIdx.y;
    int m0 = bm * 64, n0 = bn * 128;
    int tid = threadIdx.x;
    int tx = tid & 31, ty = tid >> 5;     // tx: 32 col-groups of 4, ty: 8 row-groups of 8
    float acc[8][4];
#pragma unroll
    for (int i = 0; i < 8; ++i)
#pragma unroll
        for (int j = 0; j < 4; ++j) acc[i][j] = 0.f;

    for (int kt = 0; kt < K; kt += 16) {
        {   // A tile 64x16
            int r = tid >> 2, cc = (tid & 3) * 4;
            const float4 a4 = *(const float4*)(A + (size_t)(m0 + r) * K + kt + cc);
            sA[cc + 0][r] = a4.x; sA[cc + 1][r] = a4.y; sA[cc + 2][r] = a4.z; sA[cc + 3][r] = a4.w;
        }
        {   // B tile 16x128 (two passes of 8 rows)
            int r = tid >> 5, cc = (tid & 31) * 4;
            *(float4*)(&sB[r][cc]) = *(const float4*)(W + (size_t)(kt + r) * N + n0 + cc);
            *(float4*)(&sB[r + 8][cc]) = *(const float4*)(W + (size_t)(kt + r + 8) * N + n0 + cc);
        }
        __syncthreads();
#pragma unroll
        for (int k = 0; k < 16; ++k) {
            float av[8];
#pragma unroll
            for (int i = 0; i < 8; ++i) av[i] = sA[k][ty * 8 + i];
            float bx = sB[k][tx * 4 + 0], by = sB[k][tx * 4 + 1];
            float bz = sB[k][tx * 4 + 2], bw = sB[k][tx * 4 + 3];
#pragma unroll
            for (int i = 0; i < 8; ++i) {
                acc[i][0] += av[i] * bx; acc[i][1] += av[i] * by;
                acc[i][2] += av[i] * bz; acc[i][3] += av[i] * bw;
            }
        }
        __syncthreads();
    }
    float bx = bias[n0 + tx * 4 + 0], by = bias[n0 + tx * 4 + 1];
    float bz = bias[n0 + tx * 4 + 2], bw = bias[n0 + tx * 4 + 3];
#pragma unroll
    for (int i = 0; i < 8; ++i) {
        int m = m0 + ty * 8 + i;
        float4 v;
        v.x = acc[i][0] + bx; v.y = acc[i][1] + by;
        v.z = acc[i][2] + bz; v.w = acc[i][3] + bw;
        if (do_relu) {
            v.x = fmaxf(v.x, 0.f); v.y = fmaxf(v.y, 0.f);
            v.z = fmaxf(v.z, 0.f); v.w = fmaxf(v.w, 0.f);
        }
        *(float4*)(C + (size_t)m * N + n0 + tx * 4) = v;
    }
}

__global__ __launch_bounds__(128) void k_colsum(const float* __restrict__ Y,
                                                float* __restrict__ out) {
    int c = blockIdx.x * 128 + threadIdx.x;
    int r0 = blockIdx.y * 128;
    float s = 0.f;
    for (int r = 0; r < 128; ++r) s += Y[(size_t)(r0 + r) * 768 + c];
    out[blockIdx.y * 768 + c] = s;
}

__global__ __launch_bounds__(768) void k_out(const float* __restrict__ msum,
                                             float* __restrict__ out) {
    int c = threadIdx.x;
    float s = 0.f;
#pragma unroll
    for (int i = 0; i < 32; ++i) s += msum[i * 768 + c];
    out[c] = s * (1.f / 4096.f);
}

extern "C" void kernel_launch(void* const* d_in, const int* in_sizes, int n_in,
                              void* d_out, int out_size, void* d_ws, size_t ws_size,
                              hipStream_t stream) {
    const float* x = (const float*)d_in[0];
    float* W1 = (float*)d_in[1];
    float* b1 = (float*)d_in[2];
    float* W2 = (float*)d_in[3];
    float* b2 = (float*)d_in[4];
    float* W3 = (float*)d_in[5];
    float* b3 = (float*)d_in[6];
    float* W4 = (float*)d_in[7];
    float* b4 = (float*)d_in[8];
    const int* flag = (const int*)d_in[9];
    float* wsf = (float*)d_ws;

    // ---- TTT scan: 1024 sequential tokens (x[::4]) ----
    for (int s = 0; s < 1024; ++s) {
        const float* xt = x + (size_t)s * 4 * 768;
        k_fwd1<<<256, 512, 0, stream>>>(xt, W1, wsf + OFF_Z1P, flag);
        k_fwd2<<<256, 512, 0, stream>>>(wsf + OFF_Z1P, nullptr, b1, W2, 2048,
                                        wsf + OFF_Z2P, wsf + OFF_Z2Q, flag);
        k_fwd2<<<256, 512, 0, stream>>>(wsf + OFF_Z2P, wsf + OFF_Z2Q, b2, W3, 2048,
                                        wsf + OFF_Z3P, wsf + OFF_Z3Q, flag);
        k_fwd2<<<96, 512, 0, stream>>>(wsf + OFF_Z3P, wsf + OFF_Z3Q, b3, W4, 768,
                                       wsf + OFF_Z4P, wsf + OFF_Z4Q, flag);
        k_fin<<<64, 512, 0, stream>>>(wsf, xt, b1, b2, b3, b4, flag);
        k_bwd<<<256, 512, 0, stream>>>(W4, 768, wsf + OFF_D4F, wsf + OFF_D4Q,
                                       wsf + OFF_H3F, wsf + OFF_H3Q,
                                       wsf + OFF_D3F, wsf + OFF_D3Q, wsf + OFF_SL3, flag);
        k_bwd<<<256, 512, 0, stream>>>(W3, 2048, wsf + OFF_D3F, wsf + OFF_D3Q,
                                       wsf + OFF_H2F, wsf + OFF_H2Q,
                                       wsf + OFF_D2F, wsf + OFF_D2Q, wsf + OFF_SL2, flag);
        k_bwd<<<256, 512, 0, stream>>>(W2, 2048, wsf + OFF_D2F, wsf + OFF_D2Q,
                                       wsf + OFF_H1F, wsf + OFF_H1Q,
                                       wsf + OFF_D1F, wsf + OFF_D1Q, wsf + OFF_SL1, flag);
        k_upd<<<256, 512, 0, stream>>>(s, wsf, W1, b1, W2, b2, W3, b3, W4, b4, xt, flag);
    }

    // ---- final forward over all 4096 tokens, chunked by 1024, + mean ----
    float* HA = wsf + OFF_HA;
    float* HB = wsf + OFF_HB;
    for (int ch = 0; ch < 4; ++ch) {
        const float* Xc = x + (size_t)ch * 1024 * 768;
        k_gemm<<<dim3(16, 16), 256, 0, stream>>>(Xc, W1, b1, HA, 1024, 2048, 768, 1);
        k_gemm<<<dim3(16, 16), 256, 0, stream>>>(HA, W2, b2, HB, 1024, 2048, 2048, 1);
        k_gemm<<<dim3(16, 16), 256, 0, stream>>>(HB, W3, b3, HA, 1024, 2048, 2048, 1);
        k_gemm<<<dim3(6, 16), 256, 0, stream>>>(HA, W4, b4, HB, 1024, 768, 2048, 0);
        k_colsum<<<dim3(6, 8), 128, 0, stream>>>(HB, wsf + OFF_MSUM + (size_t)ch * 8 * 768);
    }
    k_out<<<1, 768, 0, stream>>>(wsf + OFF_MSUM, (float*)d_out);
}

// Round 2
// 64387.915 us; speedup vs baseline: 1.0580x; 1.0580x over previous
//
#include <hip/hip_runtime.h>
#include <cstddef>

#define LRC 0.001f
#define DEC 0.99f

// ---------------- workspace layout (float offsets) ----------------
static const size_t OFF_Z1P = 0;            // [32][2048]
static const size_t OFF_Z2P = 65536;        // [32][2048]
static const size_t OFF_Z2Q = 131072;
static const size_t OFF_Z3P = 196608;
static const size_t OFF_Z3Q = 262144;
static const size_t OFF_Z4P = 327680;       // [32][768]
static const size_t OFF_Z4Q = 352256;
static const size_t OFF_H1F = 376832;       // 2048 each below
static const size_t OFF_H1Q = 378880;
static const size_t OFF_H2F = 380928;
static const size_t OFF_H2Q = 382976;
static const size_t OFF_H3F = 385024;
static const size_t OFF_H3Q = 387072;
static const size_t OFF_D4F = 389120;       // 768
static const size_t OFF_D4Q = 389888;       // 768
static const size_t OFF_D3F = 390656;       // 2048
static const size_t OFF_D3Q = 392704;
static const size_t OFF_D2F = 394752;
static const size_t OFF_D2Q = 396800;
static const size_t OFF_D1F = 398848;
static const size_t OFF_D1Q = 400896;
static const size_t OFF_NSQ = 402944;       // 16: 0=x,1=h1,2=h2,3=h3,4=d4
static const size_t OFF_SL3 = 402960;       // 256 per-block |d3|^2 partials
static const size_t OFF_SL2 = 403216;
static const size_t OFF_SL1 = 403472;
static const size_t OFF_BUF = 403728;       // 2 (ping-pong EMA buffer)
static const size_t OFF_CONDF = 403730;     // 1 (cond flag for current step's fused update)
static const size_t OFF_MSUM = 403732;      // [32][768]
static const size_t OFF_HA  = 428308;       // 1024*2048
static const size_t OFF_HB  = 2525460;      // 1024*2048  (end = 4622612 floats ~18.5 MB)

__device__ inline void fma4(float4& a, float s, const float4& w) {
    a.x += s * w.x; a.y += s * w.y; a.z += s * w.z; a.w += s * w.w;
}

__device__ float block_reduce_512(float v) {
    __shared__ float red[512];
    int t = threadIdx.x;
    red[t] = v;
    __syncthreads();
    for (int s = 256; s > 0; s >>= 1) {
        if (t < s) red[t] += red[t + s];
        __syncthreads();
    }
    float r = red[0];
    __syncthreads();
    return r;
}

// ---------- phase 1: fused [apply step-(s-1) W1/b1 update] + z1 partials ----------
// cond for step s-1 is computed here (slots/NSQ all written by step s-1's kernels).
__global__ __launch_bounds__(512) void k_fwd1(int step,
                                              const float* __restrict__ xt,
                                              const float* __restrict__ xprev,
                                              float* __restrict__ W1,
                                              float* __restrict__ b1,
                                              float* __restrict__ wsf,
                                              const int* __restrict__ flag) {
    if (*flag == 0) return;
    int b = blockIdx.x;               // 256 blocks
    int g = b >> 5, p = b & 31;       // g<8: 256-col group; p: K-split (24 rows)
    int tid = threadIdx.x, w = tid >> 6, lane = tid & 63;
    int c0 = g * 256 + lane * 4;
    int kb = p * 24 + w * 3;

    // issue W row loads + x loads early (independent of cond)
    float4 wv0 = *(const float4*)(W1 + (size_t)(kb + 0) * 2048 + c0);
    float4 wv1 = *(const float4*)(W1 + (size_t)(kb + 1) * 2048 + c0);
    float4 wv2 = *(const float4*)(W1 + (size_t)(kb + 2) * 2048 + c0);
    float a0 = xt[kb + 0], a1 = xt[kb + 1], a2 = xt[kb + 2];
    float4 dv = make_float4(0.f, 0.f, 0.f, 0.f);
    float u0 = 0.f, u1 = 0.f, u2 = 0.f;
    if (step > 0) {
        dv = *(const float4*)(wsf + OFF_D1Q + c0);
        u0 = LRC * xprev[kb + 0]; u1 = LRC * xprev[kb + 1]; u2 = LRC * xprev[kb + 2];
    }

    // ---- cond for step s-1 (redundant per block; ~770 broadcast loads) ----
    __shared__ float cnd[4];
    float cond = 0.f;
    if (step > 0) {
        if (w < 3) {
            const float* sl = wsf + (w == 0 ? OFF_SL1 : (w == 1 ? OFF_SL2 : OFF_SL3));
            float v = sl[lane] + sl[lane + 64] + sl[lane + 128] + sl[lane + 192];
#pragma unroll
            for (int off = 32; off > 0; off >>= 1) v += __shfl_down(v, off);
            if (lane == 0) cnd[w] = v;
        }
        __syncthreads();
        float nd1 = sqrtf(cnd[0]), nd2 = sqrtf(cnd[1]), nd3 = sqrtf(cnd[2]);
        float nx = sqrtf(wsf[OFF_NSQ + 0]);
        float nh1 = sqrtf(wsf[OFF_NSQ + 1]);
        float nh2 = sqrtf(wsf[OFF_NSQ + 2]);
        float nh3 = sqrtf(wsf[OFF_NSQ + 3]);
        float nd4 = sqrtf(wsf[OFF_NSQ + 4]);
        float surprise = nx * nd1 + nd1 + nh1 * nd2 + nd2 + nh2 * nd3 + nd3 + nh3 * nd4 + nd4;
        float bufold = wsf[OFF_BUF + ((step - 1) & 1)];
        float bufnew = (step == 1) ? surprise : (0.9f * bufold + 0.1f * surprise);
        cond = (bufnew > 0.1f) ? 1.f : 0.f;
        if (b == 0 && tid == 0) {
            wsf[OFF_BUF + (step & 1)] = bufnew;
            wsf[OFF_CONDF] = cond;
        }
    } else {
        if (b == 0 && tid == 0) wsf[OFF_CONDF] = 0.f;
    }

    if (cond != 0.f) {   // uniform branch: apply W1 update in place
        wv0.x = DEC * wv0.x - u0 * dv.x; wv0.y = DEC * wv0.y - u0 * dv.y;
        wv0.z = DEC * wv0.z - u0 * dv.z; wv0.w = DEC * wv0.w - u0 * dv.w;
        wv1.x = DEC * wv1.x - u1 * dv.x; wv1.y = DEC * wv1.y - u1 * dv.y;
        wv1.z = DEC * wv1.z - u1 * dv.z; wv1.w = DEC * wv1.w - u1 * dv.w;
        wv2.x = DEC * wv2.x - u2 * dv.x; wv2.y = DEC * wv2.y - u2 * dv.y;
        wv2.z = DEC * wv2.z - u2 * dv.z; wv2.w = DEC * wv2.w - u2 * dv.w;
        *(float4*)(W1 + (size_t)(kb + 0) * 2048 + c0) = wv0;
        *(float4*)(W1 + (size_t)(kb + 1) * 2048 + c0) = wv1;
        *(float4*)(W1 + (size_t)(kb + 2) * 2048 + c0) = wv2;
        if (b == 0) {   // b1 update (read by k_fwd2-L2 next)
            int c = tid * 4;
            float4 dq = *(const float4*)(wsf + OFF_D1Q + c);
            float4 bv = *(float4*)(b1 + c);
            bv.x = DEC * bv.x - LRC * dq.x; bv.y = DEC * bv.y - LRC * dq.y;
            bv.z = DEC * bv.z - LRC * dq.z; bv.w = DEC * bv.w - LRC * dq.w;
            *(float4*)(b1 + c) = bv;
        }
    }

    float4 acc = make_float4(0.f, 0.f, 0.f, 0.f);
    fma4(acc, a0, wv0); fma4(acc, a1, wv1); fma4(acc, a2, wv2);

    __shared__ float4 red[8][64];
    red[w][lane] = acc;
    __syncthreads();
    if (w == 0) {
        float4 s = red[0][lane];
#pragma unroll
        for (int q = 1; q < 8; ++q) {
            float4 r2 = red[q][lane];
            s.x += r2.x; s.y += r2.y; s.z += r2.z; s.w += r2.w;
        }
        *(float4*)(wsf + OFF_Z1P + (size_t)p * 2048 + c0) = s;
    }
}

// ---------- phases 2-4: fused [W_l/b_l update] + base+decayed matvec (K=2048) ----------
// zinQ == null: layer-2 (h' = 0.99*h exactly). uprev = h_{l-1}q of prev step (len 2048),
// vprev = d_l q of prev step (len Nout). bl = this layer's bias (updated here, read by NEXT kernel).
__global__ __launch_bounds__(512) void k_fwd2(const float* __restrict__ zinP,
                                              const float* __restrict__ zinQ,
                                              const float* __restrict__ bin,
                                              float* __restrict__ W, int Nout,
                                              float* __restrict__ zoutP,
                                              float* __restrict__ zoutQ,
                                              const float* __restrict__ uprev,
                                              const float* __restrict__ vprev,
                                              float* __restrict__ bl,
                                              const float* __restrict__ wsf,
                                              const int* __restrict__ flag) {
    if (*flag == 0) return;
    int b = blockIdx.x;
    int g = b >> 5, p = b & 31;
    int tid = threadIdx.x, w = tid >> 6, lane = tid & 63;
    bool upd = (wsf[OFF_CONDF] != 0.f);

    __shared__ float hs[64], hq[64], us[64];
    if (tid < 64) {
        int k = p * 64 + tid;
        float s = 0.f;
#pragma unroll 8
        for (int pp = 0; pp < 32; ++pp) s += zinP[pp * 2048 + k];
        float bv = bin[k];
        float h = fmaxf(s + bv, 0.f);
        float hqq;
        if (zinQ) {
            float sq = 0.f;
#pragma unroll 8
            for (int pp = 0; pp < 32; ++pp) sq += zinQ[pp * 2048 + k];
            hqq = fmaxf(DEC * (sq + bv), 0.f);
        } else {
            hqq = DEC * h;
        }
        hs[tid] = h; hq[tid] = hqq;
        us[tid] = upd ? (LRC * uprev[k]) : 0.f;
    }
    __syncthreads();
    int c0 = g * 256 + lane * 4;
    float4 vpv = make_float4(0.f, 0.f, 0.f, 0.f);
    if (upd) vpv = *(const float4*)(vprev + c0);
    float4 ap = make_float4(0.f, 0.f, 0.f, 0.f);
    float4 aq = make_float4(0.f, 0.f, 0.f, 0.f);
    if (upd) {
#pragma unroll
        for (int r = 0; r < 8; ++r) {
            int kk = w * 8 + r;
            float* wp = W + (size_t)(p * 64 + kk) * Nout + c0;
            float4 wv = *(const float4*)wp;
            float u = us[kk];
            wv.x = DEC * wv.x - u * vpv.x; wv.y = DEC * wv.y - u * vpv.y;
            wv.z = DEC * wv.z - u * vpv.z; wv.w = DEC * wv.w - u * vpv.w;
            *(float4*)wp = wv;
            float a = hs[kk], a2 = hq[kk];
            fma4(ap, a, wv);
            fma4(aq, a2, wv);
        }
    } else {
#pragma unroll
        for (int r = 0; r < 8; ++r) {
            int kk = w * 8 + r;
            const float4 wv = *(const float4*)(W + (size_t)(p * 64 + kk) * Nout + c0);
            float a = hs[kk], a2 = hq[kk];
            fma4(ap, a, wv);
            fma4(aq, a2, wv);
        }
    }
    if (upd && b == 0) {   // bias update for this layer (read by the NEXT kernel)
        int c = tid * 4;
        if (c < Nout) {
            float4 dq = *(const float4*)(vprev + c);
            float4 bv = *(float4*)(bl + c);
            bv.x = DEC * bv.x - LRC * dq.x; bv.y = DEC * bv.y - LRC * dq.y;
            bv.z = DEC * bv.z - LRC * dq.z; bv.w = DEC * bv.w - LRC * dq.w;
            *(float4*)(bl + c) = bv;
        }
    }
    __shared__ float4 redP[8][64];
    __shared__ float4 redQ[8][64];
    redP[w][lane] = ap; redQ[w][lane] = aq;
    __syncthreads();
    if (w == 0) {
        float4 sp = redP[0][lane], sq4 = redQ[0][lane];
#pragma unroll
        for (int q = 1; q < 8; ++q) {
            float4 r2 = redP[q][lane]; sp.x += r2.x; sp.y += r2.y; sp.z += r2.z; sp.w += r2.w;
            float4 r3 = redQ[q][lane]; sq4.x += r3.x; sq4.y += r3.y; sq4.z += r3.z; sq4.w += r3.w;
        }
        *(float4*)(zoutP + (size_t)p * Nout + c0) = sp;
        *(float4*)(zoutQ + (size_t)p * Nout + c0) = sq4;
    }
}

// ---------- phase 4b: finalize h vectors, deltas at L4, norms ----------
__global__ __launch_bounds__(512) void k_fin(float* __restrict__ wsf,
                                             const float* __restrict__ xt,
                                             const float* __restrict__ b1,
                                             const float* __restrict__ b2,
                                             const float* __restrict__ b3,
                                             const float* __restrict__ b4,
                                             const int* __restrict__ flag) {
    if (*flag == 0) return;
    int b = blockIdx.x, tid = threadIdx.x;
    if (b < 16) {
        if (tid < 128) {
            int e = b * 128 + tid;
            float s = 0.f;
#pragma unroll 8
            for (int pp = 0; pp < 32; ++pp) s += wsf[OFF_Z1P + pp * 2048 + e];
            float h = fmaxf(s + b1[e], 0.f);
            wsf[OFF_H1F + e] = h;
            wsf[OFF_H1Q + e] = DEC * h;
        }
    } else if (b < 32) {
        if (tid < 128) {
            int e = (b - 16) * 128 + tid;
            float s = 0.f, sq = 0.f;
#pragma unroll 8
            for (int pp = 0; pp < 32; ++pp) {
                s += wsf[OFF_Z2P + pp * 2048 + e];
                sq += wsf[OFF_Z2Q + pp * 2048 + e];
            }
            float bv = b2[e];
            wsf[OFF_H2F + e] = fmaxf(s + bv, 0.f);
            wsf[OFF_H2Q + e] = fmaxf(DEC * (sq + bv), 0.f);
        }
    } else if (b < 48) {
        if (tid < 128) {
            int e = (b - 32) * 128 + tid;
            float s = 0.f, sq = 0.f;
#pragma unroll 8
            for (int pp = 0; pp < 32; ++pp) {
                s += wsf[OFF_Z3P + pp * 2048 + e];
                sq += wsf[OFF_Z3Q + pp * 2048 + e];
            }
            float bv = b3[e];
            wsf[OFF_H3F + e] = fmaxf(s + bv, 0.f);
            wsf[OFF_H3Q + e] = fmaxf(DEC * (sq + bv), 0.f);
        }
    } else if (b == 48) {
        for (int e = tid; e < 768; e += 512) {
            float s = 0.f, sq = 0.f;
#pragma unroll 8
            for (int pp = 0; pp < 32; ++pp) {
                s += wsf[OFF_Z4P + pp * 768 + e];
                sq += wsf[OFF_Z4Q + pp * 768 + e];
            }
            float bv = b4[e], tv = xt[e];
            float pred = s + bv;
            float predq = DEC * (sq + bv);
            wsf[OFF_D4F + e] = 2.f * (pred - tv) * (1.f / 768.f);
            wsf[OFF_D4Q + e] = 2.f * (predq - tv) * (1.f / 768.f);
        }
    } else if (b == 49) {             // ||x||^2
        float v = 0.f;
        for (int e = tid; e < 768; e += 512) { float xv = xt[e]; v += xv * xv; }
        float s = block_reduce_512(v);
        if (tid == 0) wsf[OFF_NSQ + 0] = s;
    } else if (b == 50) {             // ||h1||^2
        float v = 0.f;
        for (int e = tid; e < 2048; e += 512) {
            float s = 0.f;
#pragma unroll 8
            for (int pp = 0; pp < 32; ++pp) s += wsf[OFF_Z1P + pp * 2048 + e];
            float h = fmaxf(s + b1[e], 0.f);
            v += h * h;
        }
        float s = block_reduce_512(v);
        if (tid == 0) wsf[OFF_NSQ + 1] = s;
    } else if (b == 51) {             // ||h2||^2
        float v = 0.f;
        for (int e = tid; e < 2048; e += 512) {
            float s = 0.f;
#pragma unroll 8
            for (int pp = 0; pp < 32; ++pp) s += wsf[OFF_Z2P + pp * 2048 + e];
            float h = fmaxf(s + b2[e], 0.f);
            v += h * h;
        }
        float s = block_reduce_512(v);
        if (tid == 0) wsf[OFF_NSQ + 2] = s;
    } else if (b == 52) {             // ||h3||^2
        float v = 0.f;
        for (int e = tid; e < 2048; e += 512) {
            float s = 0.f;
#pragma unroll 8
            for (int pp = 0; pp < 32; ++pp) s += wsf[OFF_Z3P + pp * 2048 + e];
            float h = fmaxf(s + b3[e], 0.f);
            v += h * h;
        }
        float s = block_reduce_512(v);
        if (tid == 0) wsf[OFF_NSQ + 3] = s;
    } else if (b == 53) {             // ||d4||^2
        float v = 0.f;
        for (int e = tid; e < 768; e += 512) {
            float s = 0.f;
#pragma unroll 8
            for (int pp = 0; pp < 32; ++pp) s += wsf[OFF_Z4P + pp * 768 + e];
            float d = 2.f * ((s + b4[e]) - xt[e]) * (1.f / 768.f);
            v += d * d;
        }
        float s = block_reduce_512(v);
        if (tid == 0) wsf[OFF_NSQ + 4] = s;
    }
}

// ---------- phases 5-7: fused W^T backward, wave-per-row, final outputs ----------
__global__ __launch_bounds__(512) void k_bwd(const float* __restrict__ W, int K,
                                             const float* __restrict__ dinP,
                                             const float* __restrict__ dinQ,
                                             const float* __restrict__ hP,
                                             const float* __restrict__ hQ,
                                             float* __restrict__ doutP,
                                             float* __restrict__ doutQ,
                                             float* __restrict__ slot,
                                             const int* __restrict__ flag) {
    if (*flag == 0) return;
    __shared__ float dsP[2048];
    __shared__ float dsQ[2048];
    int tid = threadIdx.x;
    for (int k = tid; k < K; k += 512) { dsP[k] = dinP[k]; dsQ[k] = dinQ[k]; }
    __syncthreads();
    int w = tid >> 6, lane = tid & 63;
    int j = blockIdx.x * 8 + w;
    const float* row = W + (size_t)j * K;
    float ap = 0.f, aq = 0.f;
    for (int k4 = lane * 4; k4 < K; k4 += 256) {
        const float4 wv = *(const float4*)(row + k4);
        ap += wv.x * dsP[k4] + wv.y * dsP[k4 + 1] + wv.z * dsP[k4 + 2] + wv.w * dsP[k4 + 3];
        aq += wv.x * dsQ[k4] + wv.y * dsQ[k4 + 1] + wv.z * dsQ[k4 + 2] + wv.w * dsQ[k4 + 3];
    }
#pragma unroll
    for (int off = 32; off > 0; off >>= 1) {
        ap += __shfl_down(ap, off);
        aq += __shfl_down(aq, off);
    }
    __shared__ float sqw[8];
    if (lane == 0) {
        float dp = (hP[j] > 0.f) ? ap : 0.f;
        float dq = (hQ[j] > 0.f) ? DEC * aq : 0.f;
        doutP[j] = dp;
        doutQ[j] = dq;
        sqw[w] = dp * dp;
    }
    __syncthreads();
    if (tid == 0) {
        float s = 0.f;
#pragma unroll
        for (int q = 0; q < 8; ++q) s += sqw[q];
        slot[blockIdx.x] = s;
    }
}

// ---------- post-loop: apply the LAST step's update (old k_upd, used once) ----------
__global__ __launch_bounds__(512) void k_upd(int step, float* __restrict__ wsf,
                                             float* __restrict__ W1, float* __restrict__ b1,
                                             float* __restrict__ W2, float* __restrict__ b2,
                                             float* __restrict__ W3, float* __restrict__ b3,
                                             float* __restrict__ W4, float* __restrict__ b4,
                                             const float* __restrict__ xt,
                                             const int* __restrict__ flag) {
    if (*flag == 0) return;
    int tid = threadIdx.x, b = blockIdx.x;
    float s3 = block_reduce_512((tid < 256) ? wsf[OFF_SL3 + tid] : 0.f);
    float s2 = block_reduce_512((tid < 256) ? wsf[OFF_SL2 + tid] : 0.f);
    float s1 = block_reduce_512((tid < 256) ? wsf[OFF_SL1 + tid] : 0.f);
    __shared__ float condsh;
    if (tid == 0) {
        float nx = sqrtf(wsf[OFF_NSQ + 0]);
        float nh1 = sqrtf(wsf[OFF_NSQ + 1]);
        float nh2 = sqrtf(wsf[OFF_NSQ + 2]);
        float nh3 = sqrtf(wsf[OFF_NSQ + 3]);
        float nd4 = sqrtf(wsf[OFF_NSQ + 4]);
        float nd3 = sqrtf(s3), nd2 = sqrtf(s2), nd1 = sqrtf(s1);
        float surprise = nx * nd1 + nd1 + nh1 * nd2 + nd2 + nh2 * nd3 + nd3 + nh3 * nd4 + nd4;
        float bufold = wsf[OFF_BUF + (step & 1)];
        float bufnew = (step == 0) ? surprise : (0.9f * bufold + 0.1f * surprise);
        wsf[OFF_BUF + ((step + 1) & 1)] = bufnew;
        condsh = (bufnew > 0.1f) ? 1.f : 0.f;
    }
    __syncthreads();
    if (condsh == 0.f) return;

    const float* d1q = wsf + OFF_D1Q;
    const float* d2q = wsf + OFF_D2Q;
    const float* d3q = wsf + OFF_D3Q;
    const float* d4q = wsf + OFF_D4Q;
    const float* h1q = wsf + OFF_H1Q;
    const float* h2q = wsf + OFF_H2Q;
    const float* h3q = wsf + OFF_H3Q;
    int c = tid * 4;
    {   // W1: 768 rows x 2048; 3 rows per block
        float4 dv = *(const float4*)(d1q + c);
#pragma unroll
        for (int r = 0; r < 3; ++r) {
            int i = b * 3 + r;
            float u = LRC * xt[i];
            float4* wp = (float4*)(W1 + (size_t)i * 2048 + c);
            float4 wv = *wp;
            wv.x = DEC * wv.x - u * dv.x; wv.y = DEC * wv.y - u * dv.y;
            wv.z = DEC * wv.z - u * dv.z; wv.w = DEC * wv.w - u * dv.w;
            *wp = wv;
        }
    }
    {   // W2
        float4 dv = *(const float4*)(d2q + c);
#pragma unroll
        for (int r = 0; r < 8; ++r) {
            int i = b * 8 + r;
            float u = LRC * h1q[i];
            float4* wp = (float4*)(W2 + (size_t)i * 2048 + c);
            float4 wv = *wp;
            wv.x = DEC * wv.x - u * dv.x; wv.y = DEC * wv.y - u * dv.y;
            wv.z = DEC * wv.z - u * dv.z; wv.w = DEC * wv.w - u * dv.w;
            *wp = wv;
        }
    }
    {   // W3
        float4 dv = *(const float4*)(d3q + c);
#pragma unroll
        for (int r = 0; r < 8; ++r) {
            int i = b * 8 + r;
            float u = LRC * h2q[i];
            float4* wp = (float4*)(W3 + (size_t)i * 2048 + c);
            float4 wv = *wp;
            wv.x = DEC * wv.x - u * dv.x; wv.y = DEC * wv.y - u * dv.y;
            wv.z = DEC * wv.z - u * dv.z; wv.w = DEC * wv.w - u * dv.w;
            *wp = wv;
        }
    }
    if (tid < 192) {   // W4: 2048x768; 8 rows per block
        float4 dv = *(const float4*)(d4q + c);
#pragma unroll
        for (int r = 0; r < 8; ++r) {
            int i = b * 8 + r;
            float u = LRC * h3q[i];
            float4* wp = (float4*)(W4 + (size_t)i * 768 + c);
            float4 wv = *wp;
            wv.x = DEC * wv.x - u * dv.x; wv.y = DEC * wv.y - u * dv.y;
            wv.z = DEC * wv.z - u * dv.z; wv.w = DEC * wv.w - u * dv.w;
            *wp = wv;
        }
    }
    if (b == 0) {
        float4 dv = *(const float4*)(d1q + c);
        float4* bp = (float4*)(b1 + c);
        float4 bv = *bp;
        bv.x = DEC * bv.x - LRC * dv.x; bv.y = DEC * bv.y - LRC * dv.y;
        bv.z = DEC * bv.z - LRC * dv.z; bv.w = DEC * bv.w - LRC * dv.w;
        *bp = bv;
    } else if (b == 1) {
        float4 dv = *(const float4*)(d2q + c);
        float4* bp = (float4*)(b2 + c);
        float4 bv = *bp;
        bv.x = DEC * bv.x - LRC * dv.x; bv.y = DEC * bv.y - LRC * dv.y;
        bv.z = DEC * bv.z - LRC * dv.z; bv.w = DEC * bv.w - LRC * dv.w;
        *bp = bv;
    } else if (b == 2) {
        float4 dv = *(const float4*)(d3q + c);
        float4* bp = (float4*)(b3 + c);
        float4 bv = *bp;
        bv.x = DEC * bv.x - LRC * dv.x; bv.y = DEC * bv.y - LRC * dv.y;
        bv.z = DEC * bv.z - LRC * dv.z; bv.w = DEC * bv.w - LRC * dv.w;
        *bp = bv;
    } else if (b == 3 && tid < 192) {
        float4 dv = *(const float4*)(d4q + c);
        float4* bp = (float4*)(b4 + c);
        float4 bv = *bp;
        bv.x = DEC * bv.x - LRC * dv.x; bv.y = DEC * bv.y - LRC * dv.y;
        bv.z = DEC * bv.z - LRC * dv.z; bv.w = DEC * bv.w - LRC * dv.w;
        *bp = bv;
    }
}

// ---------- final batch forward: fp32 tiled GEMM C = act(A@W + bias) ----------
__global__ __launch_bounds__(256) void k_gemm(const float* __restrict__ A,
                                              const float* __restrict__ W,
                                              const float* __restrict__ bias,
                                              float* __restrict__ C,
                                              int M, int N, int K, int do_relu) {
    __shared__ float sA[16][64];
    __shared__ float sB[16][128];
    int bn = blockIdx.x, bm = blockIdx.y;
    int m0 = bm * 64, n0 = bn * 128;
    int tid = threadIdx.x;
    int tx = tid & 31, ty = tid >> 5;
    float acc[8][4];
#pragma unroll
    for (int i = 0; i < 8; ++i)
#pragma unroll
        for (int j = 0; j < 4; ++j) acc[i][j] = 0.f;

    for (int kt = 0; kt < K; kt += 16) {
        {
            int r = tid >> 2, cc = (tid & 3) * 4;
            const float4 a4 = *(const float4*)(A + (size_t)(m0 + r) * K + kt + cc);
            sA[cc + 0][r] = a4.x; sA[cc + 1][r] = a4.y; sA[cc + 2][r] = a4.z; sA[cc + 3][r] = a4.w;
        }
        {
            int r = tid >> 5, cc = (tid & 31) * 4;
            *(float4*)(&sB[r][cc]) = *(const float4*)(W + (size_t)(kt + r) * N + n0 + cc);
            *(float4*)(&sB[r + 8][cc]) = *(const float4*)(W + (size_t)(kt + r + 8) * N + n0 + cc);
        }
        __syncthreads();
#pragma unroll
        for (int k = 0; k < 16; ++k) {
            float av[8];
#pragma unroll
            for (int i = 0; i < 8; ++i) av[i] = sA[k][ty * 8 + i];
            float bx = sB[k][tx * 4 + 0], by = sB[k][tx * 4 + 1];
            float bz = sB[k][tx * 4 + 2], bw = sB[k][tx * 4 + 3];
#pragma unroll
            for (int i = 0; i < 8; ++i) {
                acc[i][0] += av[i] * bx; acc[i][1] += av[i] * by;
                acc[i][2] += av[i] * bz; acc[i][3] += av[i] * bw;
            }
        }
        __syncthreads();
    }
    float bx = bias[n0 + tx * 4 + 0], by = bias[n0 + tx * 4 + 1];
    float bz = bias[n0 + tx * 4 + 2], bw = bias[n0 + tx * 4 + 3];
#pragma unroll
    for (int i = 0; i < 8; ++i) {
        int m = m0 + ty * 8 + i;
        float4 v;
        v.x = acc[i][0] + bx; v.y = acc[i][1] + by;
        v.z = acc[i][2] + bz; v.w = acc[i][3] + bw;
        if (do_relu) {
            v.x = fmaxf(v.x, 0.f); v.y = fmaxf(v.y, 0.f);
            v.z = fmaxf(v.z, 0.f); v.w = fmaxf(v.w, 0.f);
        }
        *(float4*)(C + (size_t)m * N + n0 + tx * 4) = v;
    }
}

__global__ __launch_bounds__(128) void k_colsum(const float* __restrict__ Y,
                                                float* __restrict__ out) {
    int c = blockIdx.x * 128 + threadIdx.x;
    int r0 = blockIdx.y * 128;
    float s = 0.f;
    for (int r = 0; r < 128; ++r) s += Y[(size_t)(r0 + r) * 768 + c];
    out[blockIdx.y * 768 + c] = s;
}

__global__ __launch_bounds__(768) void k_out(const float* __restrict__ msum,
                                             float* __restrict__ out) {
    int c = threadIdx.x;
    float s = 0.f;
#pragma unroll
    for (int i = 0; i < 32; ++i) s += msum[i * 768 + c];
    out[c] = s * (1.f / 4096.f);
}

extern "C" void kernel_launch(void* const* d_in, const int* in_sizes, int n_in,
                              void* d_out, int out_size, void* d_ws, size_t ws_size,
                              hipStream_t stream) {
    const float* x = (const float*)d_in[0];
    float* W1 = (float*)d_in[1];
    float* b1 = (float*)d_in[2];
    float* W2 = (float*)d_in[3];
    float* b2 = (float*)d_in[4];
    float* W3 = (float*)d_in[5];
    float* b3 = (float*)d_in[6];
    float* W4 = (float*)d_in[7];
    float* b4 = (float*)d_in[8];
    const int* flag = (const int*)d_in[9];
    float* wsf = (float*)d_ws;

    // ---- TTT scan: 1024 sequential tokens (x[::4]); step-(s-1) update fused
    //      into step s's forward kernels (8 launches/step) ----
    for (int s = 0; s < 1024; ++s) {
        const float* xt = x + (size_t)s * 4 * 768;
        const float* xprev = x + (size_t)(s > 0 ? s - 1 : 0) * 4 * 768;
        k_fwd1<<<256, 512, 0, stream>>>(s, xt, xprev, W1, b1, wsf, flag);
        k_fwd2<<<256, 512, 0, stream>>>(wsf + OFF_Z1P, nullptr, b1, W2, 2048,
                                        wsf + OFF_Z2P, wsf + OFF_Z2Q,
                                        wsf + OFF_H1Q, wsf + OFF_D2Q, b2, wsf, flag);
        k_fwd2<<<256, 512, 0, stream>>>(wsf + OFF_Z2P, wsf + OFF_Z2Q, b2, W3, 2048,
                                        wsf + OFF_Z3P, wsf + OFF_Z3Q,
                                        wsf + OFF_H2Q, wsf + OFF_D3Q, b3, wsf, flag);
        k_fwd2<<<96, 512, 0, stream>>>(wsf + OFF_Z3P, wsf + OFF_Z3Q, b3, W4, 768,
                                       wsf + OFF_Z4P, wsf + OFF_Z4Q,
                                       wsf + OFF_H3Q, wsf + OFF_D4Q, b4, wsf, flag);
        k_fin<<<64, 512, 0, stream>>>(wsf, xt, b1, b2, b3, b4, flag);
        k_bwd<<<256, 512, 0, stream>>>(W4, 768, wsf + OFF_D4F, wsf + OFF_D4Q,
                                       wsf + OFF_H3F, wsf + OFF_H3Q,
                                       wsf + OFF_D3F, wsf + OFF_D3Q, wsf + OFF_SL3, flag);
        k_bwd<<<256, 512, 0, stream>>>(W3, 2048, wsf + OFF_D3F, wsf + OFF_D3Q,
                                       wsf + OFF_H2F, wsf + OFF_H2Q,
                                       wsf + OFF_D2F, wsf + OFF_D2Q, wsf + OFF_SL2, flag);
        k_bwd<<<256, 512, 0, stream>>>(W2, 2048, wsf + OFF_D2F, wsf + OFF_D2Q,
                                       wsf + OFF_H1F, wsf + OFF_H1Q,
                                       wsf + OFF_D1F, wsf + OFF_D1Q, wsf + OFF_SL1, flag);
    }
    // apply the final (step 1023) update once
    k_upd<<<256, 512, 0, stream>>>(1023, wsf, W1, b1, W2, b2, W3, b3, W4, b4,
                                   x + (size_t)1023 * 4 * 768, flag);

    // ---- final forward over all 4096 tokens, chunked by 1024, + mean ----
    float* HA = wsf + OFF_HA;
    float* HB = wsf + OFF_HB;
    for (int ch = 0; ch < 4; ++ch) {
        const float* Xc = x + (size_t)ch * 1024 * 768;
        k_gemm<<<dim3(16, 16), 256, 0, stream>>>(Xc, W1, b1, HA, 1024, 2048, 768, 1);
        k_gemm<<<dim3(16, 16), 256, 0, stream>>>(HA, W2, b2, HB, 1024, 2048, 2048, 1);
        k_gemm<<<dim3(16, 16), 256, 0, stream>>>(HB, W3, b3, HA, 1024, 2048, 2048, 1);
        k_gemm<<<dim3(6, 16), 256, 0, stream>>>(HA, W4, b4, HB, 1024, 768, 2048, 0);
        k_colsum<<<dim3(6, 8), 128, 0, stream>>>(HB, wsf + OFF_MSUM + (size_t)ch * 8 * 768);
    }
    k_out<<<1, 768, 0, stream>>>(wsf + OFF_MSUM, (float*)d_out);
}